// Round 15
// baseline (410.271 us; speedup 1.0000x reference)
//
#include <hip/hip_runtime.h>
#include <hip/hip_bf16.h>
#include <stdint.h>

#define DDIM 256
#define NSHARD 8          // shards for deg_out atomics
#define T1 4096           // edges per bin1 block
#define NCPAD 128         // padded coarse-bin count (dst>>9, 512 rows/bin)
#define CCAP 9216         // record capacity per (rel, coarse bin); mean 8192, +11 sigma

typedef short s8v __attribute__((ext_vector_type(8)));
typedef float f4v __attribute__((ext_vector_type(4)));

__device__ __forceinline__ float bf2f(unsigned u) { return __uint_as_float(u << 16); }
__device__ __forceinline__ unsigned short f2bf(float f) {
    __hip_bfloat16 h = __float2bfloat16(f);
    return *reinterpret_cast<unsigned short*>(&h);
}
__device__ __forceinline__ unsigned pack2(float a, float b) {
    return (unsigned)f2bf(a) | ((unsigned)f2bf(b) << 16);
}

// ---------------- fused W transpose + cast: T[n][k] = bf16(W[k][n]) ----------------
__global__ void transpose3_k(const float* __restrict__ W0, const float* __restrict__ W1,
                             const float* __restrict__ W2, __hip_bfloat16* __restrict__ T0,
                             __hip_bfloat16* __restrict__ T1v, __hip_bfloat16* __restrict__ T2) {
    const float* W = (blockIdx.y == 0) ? W0 : (blockIdx.y == 1) ? W1 : W2;
    __hip_bfloat16* T = (blockIdx.y == 0) ? T0 : (blockIdx.y == 1) ? T1v : T2;
    T[blockIdx.x * DDIM + threadIdx.x] = __float2bfloat16(W[threadIdx.x * DDIM + blockIdx.x]);
}

// ---------------- deg_out count only (sharded) — unblocks the GEMMs early ----------------
__global__ void count_k(const int* __restrict__ s0, const int* __restrict__ s1,
                        const int* __restrict__ s2, int* __restrict__ cs_shard,
                        int N, int E) {
    const int i = blockIdx.x * blockDim.x + threadIdx.x;
    if (i >= E) return;
    const int sh = blockIdx.x & (NSHARD - 1);
    int* csb = cs_shard + (size_t)sh * 3 * N;
    atomicAdd(csb + s0[i], 1);
    atomicAdd(csb + N + s1[i], 1);
    atomicAdd(csb + 2 * N + s2[i], 1);
}

// ---------------- deg_out from shards, inline ----------------
__device__ __forceinline__ int deg_sum(const int* __restrict__ cs_shard, int rel, int r, int N) {
    int v = 0;
    #pragma unroll
    for (int s = 0; s < NSHARD; ++s) v += cs_shard[((size_t)s * 3 + rel) * N + r];
    return v;
}

// ==================== mega_k bodies (union LDS, 32 KB) ====================

// bin1: LDS-staged coarse binning (dense segment writes), record part only.
// LDS use: u32 stage[T1] (16 KB) + 4 x int[NCPAD] (2 KB) = 18 KB of the union.
__device__ void bin1_body(int idx, unsigned char* smem,
                          const int* __restrict__ s0, const int* __restrict__ d0,
                          const int* __restrict__ s1, const int* __restrict__ d1,
                          const int* __restrict__ s2, const int* __restrict__ d2,
                          int* __restrict__ gcur, unsigned* __restrict__ recs,
                          int N, int E, int binBlocks) {
    unsigned* stage = (unsigned*)smem;
    int* hcnt  = (int*)(smem + 16384);
    int* hoff  = (int*)(smem + 16896);
    int* lbase = (int*)(smem + 17408);
    int* lcur  = (int*)(smem + 17920);
    const int t = threadIdx.x;
    const int rel = idx / binBlocks, eb = idx % binBlocks;
    const int* s = (rel == 0) ? s0 : (rel == 1) ? s1 : s2;
    const int* d = (rel == 0) ? d0 : (rel == 1) ? d1 : d2;
    const int e0 = eb * T1;
    const int n = min(T1, E - e0);

    if (t < NCPAD) { hcnt[t] = 0; lcur[t] = 0; }
    __syncthreads();

    int ssr[T1 / 256], ddr[T1 / 256];
    #pragma unroll
    for (int k = 0; k < T1 / 256; ++k) {
        const int li = k * 256 + t;
        const bool v = li < n;
        ssr[k] = v ? s[e0 + li] : -1;
        ddr[k] = v ? d[e0 + li] : -1;
        if (v) atomicAdd(&hcnt[ddr[k] >> 9], 1);
    }
    __syncthreads();

    if (t < 64) {
        const int a0 = hcnt[2 * t], a1 = hcnt[2 * t + 1];
        const int sum = a0 + a1;
        int incl = sum;
        #pragma unroll
        for (int off = 1; off < 64; off <<= 1) {
            const int u = __shfl_up(incl, off);
            if (t >= off) incl += u;
        }
        const int excl = incl - sum;
        hoff[2 * t] = excl;
        hoff[2 * t + 1] = excl + a0;
    }
    __syncthreads();
    if (t < NCPAD) lbase[t] = atomicAdd(&gcur[rel * NCPAD + t], hcnt[t]);
    __syncthreads();

    #pragma unroll
    for (int k = 0; k < T1 / 256; ++k) {
        if (ddr[k] >= 0) {
            const int b = ddr[k] >> 9;
            const int p = atomicAdd(&lcur[b], 1);
            stage[hoff[b] + p] = (unsigned)ssr[k] | ((unsigned)(ddr[k] & 511) << 16)
                                 | ((unsigned)b << 25);
        }
    }
    __syncthreads();

    for (int i = t; i < n; i += 256) {
        const unsigned r = stage[i];
        const int b = (int)(r >> 25);
        const int pos = lbase[b] + (i - hoff[b]);
        if (pos < CCAP)
            recs[((size_t)rel * NCPAD + b) * CCAP + pos] = r & 0x1FFFFFFu;
    }
}

// dual-output GEMM, LDS double-buffered Wt (uses the full 32 KB union)
__device__ void gemm2_body(int gb, unsigned char* smem, const float* __restrict__ X,
                           const __hip_bfloat16* __restrict__ Wt0,
                           const __hip_bfloat16* __restrict__ Wt1,
                           const int* __restrict__ cs_shard, int rel0, int rel1,
                           __hip_bfloat16* __restrict__ Y0, __hip_bfloat16* __restrict__ Y1,
                           int M, int N) {
    typedef __hip_bfloat16 (*lds_t)[2][16][DDIM];
    lds_t wlds = (lds_t)smem;                       // [dbuf][rel][row][col]
    const int t = threadIdx.x;
    const int lane = t & 63, wid = t >> 6;
    const int c = lane & 15, kb = lane >> 4;
    const int rA = gb * 128 + wid * 32 + c;
    const int rB = rA + 16;
    const bool vA = rA < M, vB = rB < M;
    const int rAc = vA ? rA : (M - 1), rBc = vB ? rB : (M - 1);

    s8v xfA[8], xfB[8];
    const float* xA = X + (size_t)rAc * DDIM;
    const float* xB = X + (size_t)rBc * DDIM;
    #pragma unroll
    for (int ks = 0; ks < 8; ++ks) {
        const int k0 = ks * 32 + kb * 8;
        const f4v a0 = *reinterpret_cast<const f4v*>(xA + k0);
        const f4v a1 = *reinterpret_cast<const f4v*>(xA + k0 + 4);
        const f4v b0 = *reinterpret_cast<const f4v*>(xB + k0);
        const f4v b1 = *reinterpret_cast<const f4v*>(xB + k0 + 4);
        union { s8v v; unsigned short u[8]; } fa, fb;
        #pragma unroll
        for (int j = 0; j < 4; ++j) {
            fa.u[j] = f2bf(a0[j]); fa.u[4 + j] = f2bf(a1[j]);
            fb.u[j] = f2bf(b0[j]); fb.u[4 + j] = f2bf(b1[j]);
        }
        xfA[ks] = fa.v; xfB[ks] = fb.v;
    }

    const int dA0 = deg_sum(cs_shard, rel0, rAc, N), dB0 = deg_sum(cs_shard, rel0, rBc, N);
    const int dA1 = deg_sum(cs_shard, rel1, rAc, N), dB1 = deg_sum(cs_shard, rel1, rBc, N);
    const float s0A = rsqrtf((float)(dA0 < 1 ? 1 : dA0));
    const float s0B = rsqrtf((float)(dB0 < 1 ? 1 : dB0));
    const float s1A = rsqrtf((float)(dA1 < 1 ? 1 : dA1));
    const float s1B = rsqrtf((float)(dB1 < 1 ? 1 : dB1));

    {
        #pragma unroll
        for (int j = 0; j < 4; ++j) {
            const int q = t + j * 256;
            const int rel = q >> 9, rt = (q >> 5) & 15, ch = q & 31;
            const __hip_bfloat16* Wsrc = rel ? Wt1 : Wt0;
            const uint4 v = *reinterpret_cast<const uint4*>(Wsrc + (size_t)rt * DDIM + ch * 8);
            *reinterpret_cast<uint4*>(&(*wlds)[0 * 2 + rel][rt][(ch ^ (rt & 7)) * 8]) = v;
        }
    }

    #pragma unroll 2
    for (int nt = 0; nt < 16; ++nt) {
        __syncthreads();
        uint4 sv[4];
        if (nt + 1 < 16) {
            #pragma unroll
            for (int j = 0; j < 4; ++j) {
                const int q = t + j * 256;
                const int rel = q >> 9, rt = (q >> 5) & 15, ch = q & 31;
                const __hip_bfloat16* Wsrc = rel ? Wt1 : Wt0;
                sv[j] = *reinterpret_cast<const uint4*>(
                    Wsrc + (size_t)((nt + 1) * 16 + rt) * DDIM + ch * 8);
            }
        }

        const int buf = nt & 1;
        f4v a00 = (f4v){0.f,0.f,0.f,0.f}, a01 = a00, a10 = a00, a11 = a00;
        #pragma unroll
        for (int ks = 0; ks < 8; ++ks) {
            const int chs = ((kb + 4 * ks) ^ (c & 7)) * 8;
            const s8v wf0 = *reinterpret_cast<const s8v*>(&(*wlds)[buf * 2 + 0][c][chs]);
            const s8v wf1 = *reinterpret_cast<const s8v*>(&(*wlds)[buf * 2 + 1][c][chs]);
            a00 = __builtin_amdgcn_mfma_f32_16x16x32_bf16(wf0, xfA[ks], a00, 0, 0, 0);
            a10 = __builtin_amdgcn_mfma_f32_16x16x32_bf16(wf0, xfB[ks], a10, 0, 0, 0);
            a01 = __builtin_amdgcn_mfma_f32_16x16x32_bf16(wf1, xfA[ks], a01, 0, 0, 0);
            a11 = __builtin_amdgcn_mfma_f32_16x16x32_bf16(wf1, xfB[ks], a11, 0, 0, 0);
        }
        const int col = nt * 16 + kb * 4;
        if (vA) {
            uint2 o0, o1;
            o0.x = pack2(a00[0] * s0A, a00[1] * s0A); o0.y = pack2(a00[2] * s0A, a00[3] * s0A);
            o1.x = pack2(a01[0] * s1A, a01[1] * s1A); o1.y = pack2(a01[2] * s1A, a01[3] * s1A);
            *reinterpret_cast<uint2*>(Y0 + (size_t)rA * DDIM + col) = o0;
            *reinterpret_cast<uint2*>(Y1 + (size_t)rA * DDIM + col) = o1;
        }
        if (vB) {
            uint2 o0, o1;
            o0.x = pack2(a10[0] * s0B, a10[1] * s0B); o0.y = pack2(a10[2] * s0B, a10[3] * s0B);
            o1.x = pack2(a11[0] * s1B, a11[1] * s1B); o1.y = pack2(a11[2] * s1B, a11[3] * s1B);
            *reinterpret_cast<uint2*>(Y0 + (size_t)rB * DDIM + col) = o0;
            *reinterpret_cast<uint2*>(Y1 + (size_t)rB * DDIM + col) = o1;
        }

        if (nt + 1 < 16) {
            #pragma unroll
            for (int j = 0; j < 4; ++j) {
                const int q = t + j * 256;
                const int rel = q >> 9, rt = (q >> 5) & 15, ch = q & 31;
                *reinterpret_cast<uint4*>(&(*wlds)[(buf ^ 1) * 2 + rel][rt][(ch ^ (rt & 7)) * 8]) = sv[j];
            }
        }
    }
}

// single-output GEMM (uses 16 KB of the union)
__device__ void gemm1_body(int gb, unsigned char* smem, const float* __restrict__ X,
                           const __hip_bfloat16* __restrict__ Wt0,
                           const int* __restrict__ cs_shard, int rel0,
                           __hip_bfloat16* __restrict__ Y0, int M, int N) {
    typedef __hip_bfloat16 (*lds_t)[16][DDIM];
    lds_t wlds = (lds_t)smem;
    const int t = threadIdx.x;
    const int lane = t & 63, wid = t >> 6;
    const int c = lane & 15, kb = lane >> 4;
    const int rA = gb * 128 + wid * 32 + c;
    const int rB = rA + 16;
    const bool vA = rA < M, vB = rB < M;
    const int rAc = vA ? rA : (M - 1), rBc = vB ? rB : (M - 1);

    s8v xfA[8], xfB[8];
    const float* xA = X + (size_t)rAc * DDIM;
    const float* xB = X + (size_t)rBc * DDIM;
    #pragma unroll
    for (int ks = 0; ks < 8; ++ks) {
        const int k0 = ks * 32 + kb * 8;
        const f4v a0 = *reinterpret_cast<const f4v*>(xA + k0);
        const f4v a1 = *reinterpret_cast<const f4v*>(xA + k0 + 4);
        const f4v b0 = *reinterpret_cast<const f4v*>(xB + k0);
        const f4v b1 = *reinterpret_cast<const f4v*>(xB + k0 + 4);
        union { s8v v; unsigned short u[8]; } fa, fb;
        #pragma unroll
        for (int j = 0; j < 4; ++j) {
            fa.u[j] = f2bf(a0[j]); fa.u[4 + j] = f2bf(a1[j]);
            fb.u[j] = f2bf(b0[j]); fb.u[4 + j] = f2bf(b1[j]);
        }
        xfA[ks] = fa.v; xfB[ks] = fb.v;
    }
    const int dA0 = deg_sum(cs_shard, rel0, rAc, N), dB0 = deg_sum(cs_shard, rel0, rBc, N);
    const float s0A = rsqrtf((float)(dA0 < 1 ? 1 : dA0));
    const float s0B = rsqrtf((float)(dB0 < 1 ? 1 : dB0));

    {
        #pragma unroll
        for (int j = 0; j < 2; ++j) {
            const int q = t + j * 256;
            const int rt = (q >> 5) & 15, ch = q & 31;
            const uint4 v = *reinterpret_cast<const uint4*>(Wt0 + (size_t)rt * DDIM + ch * 8);
            *reinterpret_cast<uint4*>(&(*wlds)[0 * 16 + rt][(ch ^ (rt & 7)) * 8]) = v;
        }
    }

    #pragma unroll 2
    for (int nt = 0; nt < 16; ++nt) {
        __syncthreads();
        uint4 sv[2];
        if (nt + 1 < 16) {
            #pragma unroll
            for (int j = 0; j < 2; ++j) {
                const int q = t + j * 256;
                const int rt = (q >> 5) & 15, ch = q & 31;
                sv[j] = *reinterpret_cast<const uint4*>(
                    Wt0 + (size_t)((nt + 1) * 16 + rt) * DDIM + ch * 8);
            }
        }

        const int buf = nt & 1;
        f4v a00 = (f4v){0.f,0.f,0.f,0.f}, a10 = a00;
        #pragma unroll
        for (int ks = 0; ks < 8; ++ks) {
            const int chs = ((kb + 4 * ks) ^ (c & 7)) * 8;
            const s8v wf0 = *reinterpret_cast<const s8v*>(&(*wlds)[buf * 16 + c][chs]);
            a00 = __builtin_amdgcn_mfma_f32_16x16x32_bf16(wf0, xfA[ks], a00, 0, 0, 0);
            a10 = __builtin_amdgcn_mfma_f32_16x16x32_bf16(wf0, xfB[ks], a10, 0, 0, 0);
        }
        const int col = nt * 16 + kb * 4;
        if (vA) {
            uint2 o;
            o.x = pack2(a00[0] * s0A, a00[1] * s0A); o.y = pack2(a00[2] * s0A, a00[3] * s0A);
            *reinterpret_cast<uint2*>(Y0 + (size_t)rA * DDIM + col) = o;
        }
        if (vB) {
            uint2 o;
            o.x = pack2(a10[0] * s0B, a10[1] * s0B); o.y = pack2(a10[2] * s0B, a10[3] * s0B);
            *reinterpret_cast<uint2*>(Y0 + (size_t)rB * DDIM + col) = o;
        }

        if (nt + 1 < 16) {
            #pragma unroll
            for (int j = 0; j < 2; ++j) {
                const int q = t + j * 256;
                const int rt = (q >> 5) & 15, ch = q & 31;
                *reinterpret_cast<uint4*>(&(*wlds)[(buf ^ 1) * 16 + rt][(ch ^ (rt & 7)) * 8]) = sv[j];
            }
        }
    }
}

// ---------------- mega: gemm2 + gemm1 + bin1 in one dispatch ----------------
// GEMM blocks first (the long pole); bin1's blocks fill CU slots as GEMMs retire.
__global__ __launch_bounds__(256, 4) void mega_k(
    const int* __restrict__ s0, const int* __restrict__ d0,
    const int* __restrict__ s1, const int* __restrict__ d1,
    const int* __restrict__ s2, const int* __restrict__ d2,
    int* __restrict__ gcur, unsigned* __restrict__ recs32,
    const float* __restrict__ x_gene, const float* __restrict__ x_cell,
    const __hip_bfloat16* __restrict__ Wt_gc, const __hip_bfloat16* __restrict__ Wt_gg,
    const __hip_bfloat16* __restrict__ Wt_cg,
    const int* __restrict__ cs_shard,
    __hip_bfloat16* __restrict__ Y_gc, __hip_bfloat16* __restrict__ Y_gg,
    __hip_bfloat16* __restrict__ Y_cg,
    int N, int E, int binBlocks, int gemmBlocks) {
    __shared__ uint4 smem4[2048];                  // 32 KB union
    unsigned char* smem = (unsigned char*)smem4;
    const int bid = blockIdx.x;
    if (bid < gemmBlocks) {
        gemm2_body(bid, smem, x_gene, Wt_gc, Wt_gg, cs_shard, 0, 2, Y_gc, Y_gg, N, N);
    } else if (bid < 2 * gemmBlocks) {
        gemm1_body(bid - gemmBlocks, smem, x_cell, Wt_cg, cs_shard, 1, Y_cg, N, N);
    } else {
        bin1_body(bid - 2 * gemmBlocks, smem, s0, d0, s1, d1, s2, d2,
                  gcur, recs32, N, E, binBlocks);
    }
}

// ---------------- sort: per-coarse-bin LDS counting sort -> u16 records ----------------
__global__ __launch_bounds__(256) void sort_k(
    const unsigned* __restrict__ recs32, unsigned short* __restrict__ recs16,
    const int* __restrict__ gcur,
    int* __restrict__ row_beg, int* __restrict__ row_cnt, int N, int ncb) {
    __shared__ unsigned short stage[CCAP];   // 18 KB
    __shared__ int rc[512], ro[512], rcur[512];
    const int t = threadIdx.x;
    const int rel = blockIdx.x / ncb, bin = blockIdx.x % ncb;
    const size_t base = ((size_t)rel * NCPAD + bin) * CCAP;
    const int n = min(gcur[rel * NCPAD + bin], CCAP);

    for (int i = t; i < 512; i += 256) rc[i] = 0;
    __syncthreads();
    for (int i = t; i < n; i += 256)
        atomicAdd(&rc[(recs32[base + i] >> 16) & 511], 1);
    __syncthreads();
    if (t < 64) {
        int v[8], p[8], sum = 0;
        #pragma unroll
        for (int j = 0; j < 8; ++j) { v[j] = rc[t * 8 + j]; p[j] = sum; sum += v[j]; }
        int incl = sum;
        #pragma unroll
        for (int off = 1; off < 64; off <<= 1) {
            const int u = __shfl_up(incl, off);
            if (t >= off) incl += u;
        }
        const int excl = incl - sum;
        #pragma unroll
        for (int j = 0; j < 8; ++j) { ro[t * 8 + j] = excl + p[j]; rcur[t * 8 + j] = excl + p[j]; }
    }
    __syncthreads();
    for (int i = t; i < 512; i += 256) {
        const int grow = bin * 512 + i;
        if (grow < N) {
            row_cnt[(size_t)rel * N + grow] = rc[i];
            row_beg[(size_t)rel * N + grow] = (int)(base + ro[i]);
        }
    }
    for (int i = t; i < n; i += 256) {
        const unsigned r = recs32[base + i];
        const int pos = atomicAdd(&rcur[(r >> 16) & 511], 1);
        stage[pos] = (unsigned short)(r & 0xffffu);
    }
    __syncthreads();
    for (int i = t; i < n; i += 256)
        recs16[base + i] = stage[i];
}

// ---------------- gather helpers (u16 records) ----------------
__device__ __forceinline__ void addv(f4v& a, uint2 v) {
    a[0] += bf2f(v.x & 0xffffu);
    a[1] += bf2f(v.x >> 16);
    a[2] += bf2f(v.y & 0xffffu);
    a[3] += bf2f(v.y >> 16);
}

__device__ __forceinline__ f4v segsum(const unsigned short* __restrict__ recs, int beg, int n,
                                      const __hip_bfloat16* __restrict__ Y, int lane) {
    f4v a = (f4v){0.f, 0.f, 0.f, 0.f};
    for (int j0 = 0; j0 < n; j0 += 64) {
        const int chunk = min(64, n - j0);
        unsigned rv = 0;
        if (lane < chunk) rv = recs[beg + j0 + lane];
        int t = 0;
        for (; t + 8 <= chunk; t += 8) {
            uint2 v[8];
            #pragma unroll
            for (int i = 0; i < 8; ++i) {
                const int s = (int)__shfl(rv, t + i);
                v[i] = reinterpret_cast<const uint2*>(Y + (size_t)s * DDIM)[lane];
            }
            #pragma unroll
            for (int i = 0; i < 8; ++i) addv(a, v[i]);
        }
        if (t + 4 <= chunk) {
            uint2 v[4];
            #pragma unroll
            for (int i = 0; i < 4; ++i) {
                const int s = (int)__shfl(rv, t + i);
                v[i] = reinterpret_cast<const uint2*>(Y + (size_t)s * DDIM)[lane];
            }
            #pragma unroll
            for (int i = 0; i < 4; ++i) addv(a, v[i]);
            t += 4;
        }
        for (; t < chunk; ++t) {
            const int s = (int)__shfl(rv, t);
            addv(a, reinterpret_cast<const uint2*>(Y + (size_t)s * DDIM)[lane]);
        }
    }
    return a;
}

// ---------------- gather (+ optional 2nd relation) + LayerNorm + bias + ReLU ----------------
__global__ __launch_bounds__(256, 4) void gather_ln_k(
    const unsigned short* __restrict__ recs,
    const int* __restrict__ beg0, const int* __restrict__ cnt0,
    const __hip_bfloat16* __restrict__ Y0,
    const int* __restrict__ beg1, const int* __restrict__ cnt1,
    const __hip_bfloat16* __restrict__ Y1,          // beg1 == null -> single relation
    const float* __restrict__ gamma, const float* __restrict__ beta,
    const float* __restrict__ bias, float* __restrict__ out, int n_dst) {
    const int lane = threadIdx.x & 63, wid = threadIdx.x >> 6;
    const int row = blockIdx.x * 4 + wid;
    if (row >= n_dst) return;

    const int n0 = cnt0[row];
    f4v a = segsum(recs, beg0[row], n0, Y0, lane);
    a *= rsqrtf((float)(n0 < 1 ? 1 : n0));
    if (beg1 != nullptr) {
        const int n1 = cnt1[row];
        f4v a1 = segsum(recs, beg1[row], n1, Y1, lane);
        a += a1 * rsqrtf((float)(n1 < 1 ? 1 : n1));
    }

    float s1 = a[0] + a[1] + a[2] + a[3];
    float s2 = a[0]*a[0] + a[1]*a[1] + a[2]*a[2] + a[3]*a[3];
    #pragma unroll
    for (int off = 1; off < 64; off <<= 1) {
        s1 += __shfl_xor(s1, off);
        s2 += __shfl_xor(s2, off);
    }
    const float mu = s1 * (1.f / 256.f);
    float var = s2 * (1.f / 256.f) - mu * mu;
    var = fmaxf(var, 0.f);
    const float rs = rsqrtf(var + 1e-5f);

    const f4v g  = reinterpret_cast<const f4v*>(gamma)[lane];
    const f4v be = reinterpret_cast<const f4v*>(beta)[lane];
    const f4v bb = reinterpret_cast<const f4v*>(bias)[lane];
    f4v o;
    #pragma unroll
    for (int j = 0; j < 4; ++j) {
        float v = (a[j] - mu) * rs * g[j] + be[j] + bb[j];
        o[j] = fmaxf(v, 0.f);
    }
    reinterpret_cast<f4v*>(out + (size_t)row * DDIM)[lane] = o;
}

extern "C" void kernel_launch(void* const* d_in, const int* in_sizes, int n_in,
                              void* d_out, int out_size, void* d_ws, size_t ws_size,
                              hipStream_t stream) {
    const float* x_cell     = (const float*)d_in[0];
    const float* x_gene     = (const float*)d_in[1];
    const float* W_cg       = (const float*)d_in[2];
    const float* W_gc       = (const float*)d_in[3];
    const float* W_gg       = (const float*)d_in[4];
    const float* gamma_cell = (const float*)d_in[5];
    const float* beta_cell  = (const float*)d_in[6];
    const float* gamma_gene = (const float*)d_in[7];
    const float* beta_gene  = (const float*)d_in[8];
    const float* b_cell     = (const float*)d_in[9];
    const float* b_gene     = (const float*)d_in[10];
    const int* src_cg = (const int*)d_in[11];
    const int* dst_cg = (const int*)d_in[12];
    const int* src_gc = (const int*)d_in[13];
    const int* dst_gc = (const int*)d_in[14];
    const int* src_gg = (const int*)d_in[15];
    const int* dst_gg = (const int*)d_in[16];

    const int N = in_sizes[0] / DDIM;        // 50000
    const int E = in_sizes[11];              // 800000
    const int ncb = (N + 511) >> 9;          // 98 used coarse bins

    // ---- workspace layout (~54 MB) ----
    char* wsb = (char*)d_ws;
    size_t off = 0;
    __hip_bfloat16* Y_gc = (__hip_bfloat16*)(wsb + off); off += (size_t)N * DDIM * 2;             // 25.6 MB
    unsigned* recs32 = (unsigned*)(wsb + off);           off += (size_t)3 * NCPAD * CCAP * 4;     // 14.2 MB
    unsigned short* recs16 = (unsigned short*)(wsb + off); off += (size_t)3 * NCPAD * CCAP * 2;   // 7.1 MB
    int* row_beg = (int*)(wsb + off);                    off += (size_t)3 * N * 4;                // 600 KB
    int* row_cnt = (int*)(wsb + off);                    off += (size_t)3 * N * 4;                // 600 KB
    const size_t zeroOff = off;
    int* cs_shard = (int*)(wsb + off);                   off += (size_t)NSHARD * 3 * N * 4;       // 4.8 MB
    int* gcur     = (int*)(wsb + off);                   off += (size_t)3 * NCPAD * 4;            // 1.5 KB
    const size_t zeroBytes = off - zeroOff;
    __hip_bfloat16* Wt_gc = (__hip_bfloat16*)(wsb + off); off += (size_t)DDIM * DDIM * 2;
    __hip_bfloat16* Wt_cg = (__hip_bfloat16*)(wsb + off); off += (size_t)DDIM * DDIM * 2;
    __hip_bfloat16* Wt_gg = (__hip_bfloat16*)(wsb + off);

    int* beg_gc = row_beg, *beg_cg = row_beg + N, *beg_gg = row_beg + 2 * N;
    int* cnt_gc = row_cnt, *cnt_cg = row_cnt + N, *cnt_gg = row_cnt + 2 * N;

    // Y_cg, Y_gg live in the d_out cell-half; consumed by the gene gather before
    // the cell gather overwrites that region with the final cell output.
    float* out_cell = (float*)d_out;
    float* out_gene = out_cell + (size_t)N * DDIM;
    __hip_bfloat16* Y_cg = (__hip_bfloat16*)d_out;
    __hip_bfloat16* Y_gg = Y_cg + (size_t)N * DDIM;

    const int binBlocks   = (E + T1 - 1) / T1;     // 196
    const int gemmBlocks  = (N + 127) / 128;       // 391
    const int gatherBlocks = (N + 3) / 4;
    const int countBlocks = (E + 255) / 256;

    transpose3_k<<<dim3(DDIM, 3), DDIM, 0, stream>>>(W_gc, W_cg, W_gg, Wt_gc, Wt_cg, Wt_gg);
    hipMemsetAsync(wsb + zeroOff, 0, zeroBytes, stream);

    // deg_out only (unblocks GEMM scaling without waiting for record binning)
    count_k<<<countBlocks, 256, 0, stream>>>(src_gc, src_cg, src_gg, cs_shard, N, E);

    // gemm2 + gemm1 + bin1, one dispatch (bin1 hides in the GEMM shadow)
    mega_k<<<2 * gemmBlocks + 3 * binBlocks, 256, 0, stream>>>(
        src_gc, dst_gc, src_cg, dst_cg, src_gg, dst_gg,
        gcur, recs32, x_gene, x_cell, Wt_gc, Wt_gg, Wt_cg, cs_shard,
        Y_gc, Y_gg, Y_cg, N, E, binBlocks, gemmBlocks);

    sort_k<<<3 * ncb, 256, 0, stream>>>(recs32, recs16, gcur, row_beg, row_cnt, N, ncb);

    // gene: cg + gg fused gather + LN
    gather_ln_k<<<gatherBlocks, 256, 0, stream>>>(recs16, beg_cg, cnt_cg, Y_cg,
                                                  beg_gg, cnt_gg, Y_gg,
                                                  gamma_gene, beta_gene, b_gene, out_gene, N);
    // cell: gc gather + LN (overwrites Y_cg/Y_gg region)
    gather_ln_k<<<gatherBlocks, 256, 0, stream>>>(recs16, beg_gc, cnt_gc, Y_gc,
                                                  nullptr, nullptr, nullptr,
                                                  gamma_cell, beta_cell, b_cell, out_cell, N);
}

// Round 16
// 372.697 us; speedup vs baseline: 1.1008x; 1.1008x over previous
//
#include <hip/hip_runtime.h>
#include <hip/hip_bf16.h>
#include <stdint.h>

#define DDIM 256
#define NSHARD 8          // shards for deg_out atomics
#define T1 4096           // edges per bin1 block
#define NCPAD 128         // padded coarse-bin count (dst>>9, 512 rows/bin)
#define CCAP 9216         // record capacity per (rel, coarse bin); mean 8192, +11 sigma

typedef short s8v __attribute__((ext_vector_type(8)));
typedef float f4v __attribute__((ext_vector_type(4)));

__device__ __forceinline__ float bf2f(unsigned u) { return __uint_as_float(u << 16); }
__device__ __forceinline__ unsigned short f2bf(float f) {
    __hip_bfloat16 h = __float2bfloat16(f);
    return *reinterpret_cast<unsigned short*>(&h);
}
__device__ __forceinline__ unsigned pack2(float a, float b) {
    return (unsigned)f2bf(a) | ((unsigned)f2bf(b) << 16);
}

// ---------------- fused W transpose + cast: T[n][k] = bf16(W[k][n]) ----------------
__global__ void transpose3_k(const float* __restrict__ W0, const float* __restrict__ W1,
                             const float* __restrict__ W2, __hip_bfloat16* __restrict__ T0,
                             __hip_bfloat16* __restrict__ T1v, __hip_bfloat16* __restrict__ T2) {
    const float* W = (blockIdx.y == 0) ? W0 : (blockIdx.y == 1) ? W1 : W2;
    __hip_bfloat16* T = (blockIdx.y == 0) ? T0 : (blockIdx.y == 1) ? T1v : T2;
    T[blockIdx.x * DDIM + threadIdx.x] = __float2bfloat16(W[threadIdx.x * DDIM + blockIdx.x]);
}

// ---------------- pass 1: LDS-staged coarse binning (dense segment writes) ----------------
// record = src | (dst&511)<<16 | bin<<25 ; bin = dst>>9.
__global__ __launch_bounds__(256) void bin1_k(
    const int* __restrict__ s0, const int* __restrict__ d0,
    const int* __restrict__ s1, const int* __restrict__ d1,
    const int* __restrict__ s2, const int* __restrict__ d2,
    int* __restrict__ cs_shard,      // [NSHARD][3][N]
    int* __restrict__ gcur,          // [3][NCPAD]
    unsigned* __restrict__ recs,     // [3][NCPAD][CCAP]
    int N, int E) {
    __shared__ unsigned stage[T1];           // 16 KB
    __shared__ int hcnt[NCPAD], hoff[NCPAD], lbase[NCPAD], lcur[NCPAD];
    const int t = threadIdx.x;
    const int rel = blockIdx.y;
    const int* s = (rel == 0) ? s0 : (rel == 1) ? s1 : s2;
    const int* d = (rel == 0) ? d0 : (rel == 1) ? d1 : d2;
    const int e0 = blockIdx.x * T1;
    const int n = min(T1, E - e0);
    int* csb = cs_shard + ((size_t)(blockIdx.x & (NSHARD - 1)) * 3 + rel) * N;

    if (t < NCPAD) { hcnt[t] = 0; lcur[t] = 0; }
    __syncthreads();

    int ssr[T1 / 256], ddr[T1 / 256];
    #pragma unroll
    for (int k = 0; k < T1 / 256; ++k) {
        const int li = k * 256 + t;
        const bool v = li < n;
        ssr[k] = v ? s[e0 + li] : -1;
        ddr[k] = v ? d[e0 + li] : -1;
        if (v) {
            atomicAdd(&hcnt[ddr[k] >> 9], 1);
            atomicAdd(&csb[ssr[k]], 1);
        }
    }
    __syncthreads();

    if (t < 64) {
        const int a0 = hcnt[2 * t], a1 = hcnt[2 * t + 1];
        const int sum = a0 + a1;
        int incl = sum;
        #pragma unroll
        for (int off = 1; off < 64; off <<= 1) {
            const int u = __shfl_up(incl, off);
            if (t >= off) incl += u;
        }
        const int excl = incl - sum;
        hoff[2 * t] = excl;
        hoff[2 * t + 1] = excl + a0;
    }
    __syncthreads();
    if (t < NCPAD) lbase[t] = atomicAdd(&gcur[rel * NCPAD + t], hcnt[t]);
    __syncthreads();

    #pragma unroll
    for (int k = 0; k < T1 / 256; ++k) {
        if (ddr[k] >= 0) {
            const int b = ddr[k] >> 9;
            const int p = atomicAdd(&lcur[b], 1);
            stage[hoff[b] + p] = (unsigned)ssr[k] | ((unsigned)(ddr[k] & 511) << 16)
                                 | ((unsigned)b << 25);
        }
    }
    __syncthreads();

    for (int i = t; i < n; i += 256) {
        const unsigned r = stage[i];
        const int b = (int)(r >> 25);
        const int pos = lbase[b] + (i - hoff[b]);
        if (pos < CCAP)
            recs[((size_t)rel * NCPAD + b) * CCAP + pos] = r & 0x1FFFFFFu;
    }
}

// ---------------- deg_out from shards, inline ----------------
__device__ __forceinline__ int deg_sum(const int* __restrict__ cs_shard, int rel, int r, int N) {
    int v = 0;
    #pragma unroll
    for (int s = 0; s < NSHARD; ++s) v += cs_shard[((size_t)s * 3 + rel) * N + r];
    return v;
}

// ==================== mid_k bodies (union LDS, 32 KB) ====================

// sort: per-coarse-bin counting sort by dst row; emits u16 src records.
__device__ void sort_body(int sb, unsigned char* smem,
                          const unsigned* __restrict__ recs32,
                          unsigned short* __restrict__ recs16,
                          const int* __restrict__ gcur,
                          int* __restrict__ row_beg, int* __restrict__ row_cnt,
                          int N, int ncb) {
    unsigned short* stage = (unsigned short*)smem;                 // [CCAP]
    int* rc   = (int*)(smem + 18432);
    int* ro   = (int*)(smem + 20480);
    int* rcur = (int*)(smem + 22528);
    const int t = threadIdx.x;
    const int rel = sb / ncb, bin = sb % ncb;
    const size_t base = ((size_t)rel * NCPAD + bin) * CCAP;
    const int n = min(gcur[rel * NCPAD + bin], CCAP);

    for (int i = t; i < 512; i += 256) rc[i] = 0;
    __syncthreads();
    for (int i = t; i < n; i += 256)
        atomicAdd(&rc[(recs32[base + i] >> 16) & 511], 1);
    __syncthreads();
    if (t < 64) {
        int v[8], p[8], sum = 0;
        #pragma unroll
        for (int j = 0; j < 8; ++j) { v[j] = rc[t * 8 + j]; p[j] = sum; sum += v[j]; }
        int incl = sum;
        #pragma unroll
        for (int off = 1; off < 64; off <<= 1) {
            const int u = __shfl_up(incl, off);
            if (t >= off) incl += u;
        }
        const int excl = incl - sum;
        #pragma unroll
        for (int j = 0; j < 8; ++j) { ro[t * 8 + j] = excl + p[j]; rcur[t * 8 + j] = excl + p[j]; }
    }
    __syncthreads();
    for (int i = t; i < 512; i += 256) {
        const int grow = bin * 512 + i;
        if (grow < N) {
            row_cnt[(size_t)rel * N + grow] = rc[i];
            row_beg[(size_t)rel * N + grow] = (int)(base + ro[i]);
        }
    }
    for (int i = t; i < n; i += 256) {
        const unsigned r = recs32[base + i];
        const int pos = atomicAdd(&rcur[(r >> 16) & 511], 1);
        stage[pos] = (unsigned short)(r & 0xffffu);
    }
    __syncthreads();
    for (int i = t; i < n; i += 256)
        recs16[base + i] = stage[i];
}

// dual-output GEMM, LDS double-buffered Wt (uses the full 32 KB union)
__device__ void gemm2_body(int gb, unsigned char* smem, const float* __restrict__ X,
                           const __hip_bfloat16* __restrict__ Wt0,
                           const __hip_bfloat16* __restrict__ Wt1,
                           const int* __restrict__ cs_shard, int rel0, int rel1,
                           __hip_bfloat16* __restrict__ Y0, __hip_bfloat16* __restrict__ Y1,
                           int M, int N) {
    typedef __hip_bfloat16 (*lds_t)[2][16][DDIM];
    lds_t wlds = (lds_t)smem;                       // [dbuf][rel][row][col]
    const int t = threadIdx.x;
    const int lane = t & 63, wid = t >> 6;
    const int c = lane & 15, kb = lane >> 4;
    const int rA = gb * 128 + wid * 32 + c;
    const int rB = rA + 16;
    const bool vA = rA < M, vB = rB < M;
    const int rAc = vA ? rA : (M - 1), rBc = vB ? rB : (M - 1);

    s8v xfA[8], xfB[8];
    const float* xA = X + (size_t)rAc * DDIM;
    const float* xB = X + (size_t)rBc * DDIM;
    #pragma unroll
    for (int ks = 0; ks < 8; ++ks) {
        const int k0 = ks * 32 + kb * 8;
        const f4v a0 = *reinterpret_cast<const f4v*>(xA + k0);
        const f4v a1 = *reinterpret_cast<const f4v*>(xA + k0 + 4);
        const f4v b0 = *reinterpret_cast<const f4v*>(xB + k0);
        const f4v b1 = *reinterpret_cast<const f4v*>(xB + k0 + 4);
        union { s8v v; unsigned short u[8]; } fa, fb;
        #pragma unroll
        for (int j = 0; j < 4; ++j) {
            fa.u[j] = f2bf(a0[j]); fa.u[4 + j] = f2bf(a1[j]);
            fb.u[j] = f2bf(b0[j]); fb.u[4 + j] = f2bf(b1[j]);
        }
        xfA[ks] = fa.v; xfB[ks] = fb.v;
    }

    const int dA0 = deg_sum(cs_shard, rel0, rAc, N), dB0 = deg_sum(cs_shard, rel0, rBc, N);
    const int dA1 = deg_sum(cs_shard, rel1, rAc, N), dB1 = deg_sum(cs_shard, rel1, rBc, N);
    const float s0A = rsqrtf((float)(dA0 < 1 ? 1 : dA0));
    const float s0B = rsqrtf((float)(dB0 < 1 ? 1 : dB0));
    const float s1A = rsqrtf((float)(dA1 < 1 ? 1 : dA1));
    const float s1B = rsqrtf((float)(dB1 < 1 ? 1 : dB1));

    {
        #pragma unroll
        for (int j = 0; j < 4; ++j) {
            const int q = t + j * 256;
            const int rel = q >> 9, rt = (q >> 5) & 15, ch = q & 31;
            const __hip_bfloat16* Wsrc = rel ? Wt1 : Wt0;
            const uint4 v = *reinterpret_cast<const uint4*>(Wsrc + (size_t)rt * DDIM + ch * 8);
            *reinterpret_cast<uint4*>(&(*wlds)[0 * 2 + rel][rt][(ch ^ (rt & 7)) * 8]) = v;
        }
    }

    #pragma unroll 2
    for (int nt = 0; nt < 16; ++nt) {
        __syncthreads();
        uint4 sv[4];
        if (nt + 1 < 16) {
            #pragma unroll
            for (int j = 0; j < 4; ++j) {
                const int q = t + j * 256;
                const int rel = q >> 9, rt = (q >> 5) & 15, ch = q & 31;
                const __hip_bfloat16* Wsrc = rel ? Wt1 : Wt0;
                sv[j] = *reinterpret_cast<const uint4*>(
                    Wsrc + (size_t)((nt + 1) * 16 + rt) * DDIM + ch * 8);
            }
        }

        const int buf = nt & 1;
        f4v a00 = (f4v){0.f,0.f,0.f,0.f}, a01 = a00, a10 = a00, a11 = a00;
        #pragma unroll
        for (int ks = 0; ks < 8; ++ks) {
            const int chs = ((kb + 4 * ks) ^ (c & 7)) * 8;
            const s8v wf0 = *reinterpret_cast<const s8v*>(&(*wlds)[buf * 2 + 0][c][chs]);
            const s8v wf1 = *reinterpret_cast<const s8v*>(&(*wlds)[buf * 2 + 1][c][chs]);
            a00 = __builtin_amdgcn_mfma_f32_16x16x32_bf16(wf0, xfA[ks], a00, 0, 0, 0);
            a10 = __builtin_amdgcn_mfma_f32_16x16x32_bf16(wf0, xfB[ks], a10, 0, 0, 0);
            a01 = __builtin_amdgcn_mfma_f32_16x16x32_bf16(wf1, xfA[ks], a01, 0, 0, 0);
            a11 = __builtin_amdgcn_mfma_f32_16x16x32_bf16(wf1, xfB[ks], a11, 0, 0, 0);
        }
        const int col = nt * 16 + kb * 4;
        if (vA) {
            uint2 o0, o1;
            o0.x = pack2(a00[0] * s0A, a00[1] * s0A); o0.y = pack2(a00[2] * s0A, a00[3] * s0A);
            o1.x = pack2(a01[0] * s1A, a01[1] * s1A); o1.y = pack2(a01[2] * s1A, a01[3] * s1A);
            *reinterpret_cast<uint2*>(Y0 + (size_t)rA * DDIM + col) = o0;
            *reinterpret_cast<uint2*>(Y1 + (size_t)rA * DDIM + col) = o1;
        }
        if (vB) {
            uint2 o0, o1;
            o0.x = pack2(a10[0] * s0B, a10[1] * s0B); o0.y = pack2(a10[2] * s0B, a10[3] * s0B);
            o1.x = pack2(a11[0] * s1B, a11[1] * s1B); o1.y = pack2(a11[2] * s1B, a11[3] * s1B);
            *reinterpret_cast<uint2*>(Y0 + (size_t)rB * DDIM + col) = o0;
            *reinterpret_cast<uint2*>(Y1 + (size_t)rB * DDIM + col) = o1;
        }

        if (nt + 1 < 16) {
            #pragma unroll
            for (int j = 0; j < 4; ++j) {
                const int q = t + j * 256;
                const int rel = q >> 9, rt = (q >> 5) & 15, ch = q & 31;
                *reinterpret_cast<uint4*>(&(*wlds)[(buf ^ 1) * 2 + rel][rt][(ch ^ (rt & 7)) * 8]) = sv[j];
            }
        }
    }
}

// single-output GEMM (uses 16 KB of the union)
__device__ void gemm1_body(int gb, unsigned char* smem, const float* __restrict__ X,
                           const __hip_bfloat16* __restrict__ Wt0,
                           const int* __restrict__ cs_shard, int rel0,
                           __hip_bfloat16* __restrict__ Y0, int M, int N) {
    typedef __hip_bfloat16 (*lds_t)[16][DDIM];
    lds_t wlds = (lds_t)smem;
    const int t = threadIdx.x;
    const int lane = t & 63, wid = t >> 6;
    const int c = lane & 15, kb = lane >> 4;
    const int rA = gb * 128 + wid * 32 + c;
    const int rB = rA + 16;
    const bool vA = rA < M, vB = rB < M;
    const int rAc = vA ? rA : (M - 1), rBc = vB ? rB : (M - 1);

    s8v xfA[8], xfB[8];
    const float* xA = X + (size_t)rAc * DDIM;
    const float* xB = X + (size_t)rBc * DDIM;
    #pragma unroll
    for (int ks = 0; ks < 8; ++ks) {
        const int k0 = ks * 32 + kb * 8;
        const f4v a0 = *reinterpret_cast<const f4v*>(xA + k0);
        const f4v a1 = *reinterpret_cast<const f4v*>(xA + k0 + 4);
        const f4v b0 = *reinterpret_cast<const f4v*>(xB + k0);
        const f4v b1 = *reinterpret_cast<const f4v*>(xB + k0 + 4);
        union { s8v v; unsigned short u[8]; } fa, fb;
        #pragma unroll
        for (int j = 0; j < 4; ++j) {
            fa.u[j] = f2bf(a0[j]); fa.u[4 + j] = f2bf(a1[j]);
            fb.u[j] = f2bf(b0[j]); fb.u[4 + j] = f2bf(b1[j]);
        }
        xfA[ks] = fa.v; xfB[ks] = fb.v;
    }
    const int dA0 = deg_sum(cs_shard, rel0, rAc, N), dB0 = deg_sum(cs_shard, rel0, rBc, N);
    const float s0A = rsqrtf((float)(dA0 < 1 ? 1 : dA0));
    const float s0B = rsqrtf((float)(dB0 < 1 ? 1 : dB0));

    {
        #pragma unroll
        for (int j = 0; j < 2; ++j) {
            const int q = t + j * 256;
            const int rt = (q >> 5) & 15, ch = q & 31;
            const uint4 v = *reinterpret_cast<const uint4*>(Wt0 + (size_t)rt * DDIM + ch * 8);
            *reinterpret_cast<uint4*>(&(*wlds)[0 * 16 + rt][(ch ^ (rt & 7)) * 8]) = v;
        }
    }

    #pragma unroll 2
    for (int nt = 0; nt < 16; ++nt) {
        __syncthreads();
        uint4 sv[2];
        if (nt + 1 < 16) {
            #pragma unroll
            for (int j = 0; j < 2; ++j) {
                const int q = t + j * 256;
                const int rt = (q >> 5) & 15, ch = q & 31;
                sv[j] = *reinterpret_cast<const uint4*>(
                    Wt0 + (size_t)((nt + 1) * 16 + rt) * DDIM + ch * 8);
            }
        }

        const int buf = nt & 1;
        f4v a00 = (f4v){0.f,0.f,0.f,0.f}, a10 = a00;
        #pragma unroll
        for (int ks = 0; ks < 8; ++ks) {
            const int chs = ((kb + 4 * ks) ^ (c & 7)) * 8;
            const s8v wf0 = *reinterpret_cast<const s8v*>(&(*wlds)[buf * 16 + c][chs]);
            a00 = __builtin_amdgcn_mfma_f32_16x16x32_bf16(wf0, xfA[ks], a00, 0, 0, 0);
            a10 = __builtin_amdgcn_mfma_f32_16x16x32_bf16(wf0, xfB[ks], a10, 0, 0, 0);
        }
        const int col = nt * 16 + kb * 4;
        if (vA) {
            uint2 o;
            o.x = pack2(a00[0] * s0A, a00[1] * s0A); o.y = pack2(a00[2] * s0A, a00[3] * s0A);
            *reinterpret_cast<uint2*>(Y0 + (size_t)rA * DDIM + col) = o;
        }
        if (vB) {
            uint2 o;
            o.x = pack2(a10[0] * s0B, a10[1] * s0B); o.y = pack2(a10[2] * s0B, a10[3] * s0B);
            *reinterpret_cast<uint2*>(Y0 + (size_t)rB * DDIM + col) = o;
        }

        if (nt + 1 < 16) {
            #pragma unroll
            for (int j = 0; j < 2; ++j) {
                const int q = t + j * 256;
                const int rt = (q >> 5) & 15, ch = q & 31;
                *reinterpret_cast<uint4*>(&(*wlds)[(buf ^ 1) * 16 + rt][(ch ^ (rt & 7)) * 8]) = sv[j];
            }
        }
    }
}

// ---------------- mid: gemm2 + gemm1 + sort in one dispatch (32 KB union LDS) ----------------
// launch_bounds(256,2): VGPR budget 256 so gemm2's X fragments + prefetch stay
// register-resident (the (256,4) build collapsed to 64 VGPRs -> per-nt spills).
__global__ __launch_bounds__(256, 2) void mid_k(
    const unsigned* __restrict__ recs32, unsigned short* __restrict__ recs16,
    const int* __restrict__ gcur,
    int* __restrict__ row_beg, int* __restrict__ row_cnt,
    const float* __restrict__ x_gene, const float* __restrict__ x_cell,
    const __hip_bfloat16* __restrict__ Wt_gc, const __hip_bfloat16* __restrict__ Wt_gg,
    const __hip_bfloat16* __restrict__ Wt_cg,
    const int* __restrict__ cs_shard,
    __hip_bfloat16* __restrict__ Y_gc, __hip_bfloat16* __restrict__ Y_gg,
    __hip_bfloat16* __restrict__ Y_cg,
    int N, int ncb, int gemmBlocks) {
    __shared__ uint4 smem4[2048];                  // 32 KB union
    unsigned char* smem = (unsigned char*)smem4;
    const int bid = blockIdx.x;
    if (bid < gemmBlocks) {
        gemm2_body(bid, smem, x_gene, Wt_gc, Wt_gg, cs_shard, 0, 2, Y_gc, Y_gg, N, N);
    } else if (bid < 2 * gemmBlocks) {
        gemm1_body(bid - gemmBlocks, smem, x_cell, Wt_cg, cs_shard, 1, Y_cg, N, N);
    } else {
        sort_body(bid - 2 * gemmBlocks, smem, recs32, recs16, gcur,
                  row_beg, row_cnt, N, ncb);
    }
}

// ---------------- gather helpers (u16 records) ----------------
__device__ __forceinline__ void addv(f4v& a, uint2 v) {
    a[0] += bf2f(v.x & 0xffffu);
    a[1] += bf2f(v.x >> 16);
    a[2] += bf2f(v.y & 0xffffu);
    a[3] += bf2f(v.y >> 16);
}

__device__ __forceinline__ f4v segsum(const unsigned short* __restrict__ recs, int beg, int n,
                                      const __hip_bfloat16* __restrict__ Y, int lane) {
    f4v a = (f4v){0.f, 0.f, 0.f, 0.f};
    for (int j0 = 0; j0 < n; j0 += 64) {
        const int chunk = min(64, n - j0);
        unsigned rv = 0;
        if (lane < chunk) rv = recs[beg + j0 + lane];
        int t = 0;
        for (; t + 8 <= chunk; t += 8) {
            uint2 v[8];
            #pragma unroll
            for (int i = 0; i < 8; ++i) {
                const int s = (int)__shfl(rv, t + i);
                v[i] = reinterpret_cast<const uint2*>(Y + (size_t)s * DDIM)[lane];
            }
            #pragma unroll
            for (int i = 0; i < 8; ++i) addv(a, v[i]);
        }
        if (t + 4 <= chunk) {
            uint2 v[4];
            #pragma unroll
            for (int i = 0; i < 4; ++i) {
                const int s = (int)__shfl(rv, t + i);
                v[i] = reinterpret_cast<const uint2*>(Y + (size_t)s * DDIM)[lane];
            }
            #pragma unroll
            for (int i = 0; i < 4; ++i) addv(a, v[i]);
            t += 4;
        }
        for (; t < chunk; ++t) {
            const int s = (int)__shfl(rv, t);
            addv(a, reinterpret_cast<const uint2*>(Y + (size_t)s * DDIM)[lane]);
        }
    }
    return a;
}

// ---------------- gather (+ optional 2nd relation) + LayerNorm + bias + ReLU ----------------
__global__ __launch_bounds__(256, 4) void gather_ln_k(
    const unsigned short* __restrict__ recs,
    const int* __restrict__ beg0, const int* __restrict__ cnt0,
    const __hip_bfloat16* __restrict__ Y0,
    const int* __restrict__ beg1, const int* __restrict__ cnt1,
    const __hip_bfloat16* __restrict__ Y1,          // beg1 == null -> single relation
    const float* __restrict__ gamma, const float* __restrict__ beta,
    const float* __restrict__ bias, float* __restrict__ out, int n_dst) {
    const int lane = threadIdx.x & 63, wid = threadIdx.x >> 6;
    const int row = blockIdx.x * 4 + wid;
    if (row >= n_dst) return;

    const int n0 = cnt0[row];
    f4v a = segsum(recs, beg0[row], n0, Y0, lane);
    a *= rsqrtf((float)(n0 < 1 ? 1 : n0));
    if (beg1 != nullptr) {
        const int n1 = cnt1[row];
        f4v a1 = segsum(recs, beg1[row], n1, Y1, lane);
        a += a1 * rsqrtf((float)(n1 < 1 ? 1 : n1));
    }

    float s1 = a[0] + a[1] + a[2] + a[3];
    float s2 = a[0]*a[0] + a[1]*a[1] + a[2]*a[2] + a[3]*a[3];
    #pragma unroll
    for (int off = 1; off < 64; off <<= 1) {
        s1 += __shfl_xor(s1, off);
        s2 += __shfl_xor(s2, off);
    }
    const float mu = s1 * (1.f / 256.f);
    float var = s2 * (1.f / 256.f) - mu * mu;
    var = fmaxf(var, 0.f);
    const float rs = rsqrtf(var + 1e-5f);

    const f4v g  = reinterpret_cast<const f4v*>(gamma)[lane];
    const f4v be = reinterpret_cast<const f4v*>(beta)[lane];
    const f4v bb = reinterpret_cast<const f4v*>(bias)[lane];
    f4v o;
    #pragma unroll
    for (int j = 0; j < 4; ++j) {
        float v = (a[j] - mu) * rs * g[j] + be[j] + bb[j];
        o[j] = fmaxf(v, 0.f);
    }
    reinterpret_cast<f4v*>(out + (size_t)row * DDIM)[lane] = o;
}

extern "C" void kernel_launch(void* const* d_in, const int* in_sizes, int n_in,
                              void* d_out, int out_size, void* d_ws, size_t ws_size,
                              hipStream_t stream) {
    const float* x_cell     = (const float*)d_in[0];
    const float* x_gene     = (const float*)d_in[1];
    const float* W_cg       = (const float*)d_in[2];
    const float* W_gc       = (const float*)d_in[3];
    const float* W_gg       = (const float*)d_in[4];
    const float* gamma_cell = (const float*)d_in[5];
    const float* beta_cell  = (const float*)d_in[6];
    const float* gamma_gene = (const float*)d_in[7];
    const float* beta_gene  = (const float*)d_in[8];
    const float* b_cell     = (const float*)d_in[9];
    const float* b_gene     = (const float*)d_in[10];
    const int* src_cg = (const int*)d_in[11];
    const int* dst_cg = (const int*)d_in[12];
    const int* src_gc = (const int*)d_in[13];
    const int* dst_gc = (const int*)d_in[14];
    const int* src_gg = (const int*)d_in[15];
    const int* dst_gg = (const int*)d_in[16];

    const int N = in_sizes[0] / DDIM;        // 50000
    const int E = in_sizes[11];              // 800000
    const int ncb = (N + 511) >> 9;          // 98 used coarse bins

    // ---- workspace layout (~54 MB) ----
    char* wsb = (char*)d_ws;
    size_t off = 0;
    __hip_bfloat16* Y_gc = (__hip_bfloat16*)(wsb + off); off += (size_t)N * DDIM * 2;             // 25.6 MB
    unsigned* recs32 = (unsigned*)(wsb + off);           off += (size_t)3 * NCPAD * CCAP * 4;     // 14.2 MB
    unsigned short* recs16 = (unsigned short*)(wsb + off); off += (size_t)3 * NCPAD * CCAP * 2;   // 7.1 MB
    int* row_beg = (int*)(wsb + off);                    off += (size_t)3 * N * 4;                // 600 KB
    int* row_cnt = (int*)(wsb + off);                    off += (size_t)3 * N * 4;                // 600 KB
    const size_t zeroOff = off;
    int* cs_shard = (int*)(wsb + off);                   off += (size_t)NSHARD * 3 * N * 4;       // 4.8 MB
    int* gcur     = (int*)(wsb + off);                   off += (size_t)3 * NCPAD * 4;            // 1.5 KB
    const size_t zeroBytes = off - zeroOff;
    __hip_bfloat16* Wt_gc = (__hip_bfloat16*)(wsb + off); off += (size_t)DDIM * DDIM * 2;
    __hip_bfloat16* Wt_cg = (__hip_bfloat16*)(wsb + off); off += (size_t)DDIM * DDIM * 2;
    __hip_bfloat16* Wt_gg = (__hip_bfloat16*)(wsb + off);

    int* beg_gc = row_beg, *beg_cg = row_beg + N, *beg_gg = row_beg + 2 * N;
    int* cnt_gc = row_cnt, *cnt_cg = row_cnt + N, *cnt_gg = row_cnt + 2 * N;

    // Y_cg, Y_gg live in the d_out cell-half; consumed by the gene gather before
    // the cell gather overwrites that region with the final cell output.
    float* out_cell = (float*)d_out;
    float* out_gene = out_cell + (size_t)N * DDIM;
    __hip_bfloat16* Y_cg = (__hip_bfloat16*)d_out;
    __hip_bfloat16* Y_gg = Y_cg + (size_t)N * DDIM;

    const int binBlocks  = (E + T1 - 1) / T1;
    const int gemmBlocks = (N + 127) / 128;
    const int gatherBlocks = (N + 3) / 4;

    transpose3_k<<<dim3(DDIM, 3), DDIM, 0, stream>>>(W_gc, W_cg, W_gg, Wt_gc, Wt_cg, Wt_gg);
    hipMemsetAsync(wsb + zeroOff, 0, zeroBytes, stream);

    // relations: 0=gc, 1=cg, 2=gg
    bin1_k<<<dim3(binBlocks, 3), 256, 0, stream>>>(src_gc, dst_gc, src_cg, dst_cg,
                                                   src_gg, dst_gg, cs_shard, gcur, recs32, N, E);

    // gemm2 + gemm1 + sort, one dispatch (GEMM blocks first; sort hides in their shadow)
    mid_k<<<2 * gemmBlocks + 3 * ncb, 256, 0, stream>>>(
        recs32, recs16, gcur, row_beg, row_cnt, x_gene, x_cell,
        Wt_gc, Wt_gg, Wt_cg, cs_shard, Y_gc, Y_gg, Y_cg, N, ncb, gemmBlocks);

    // gene: cg + gg fused gather + LN
    gather_ln_k<<<gatherBlocks, 256, 0, stream>>>(recs16, beg_cg, cnt_cg, Y_cg,
                                                  beg_gg, cnt_gg, Y_gg,
                                                  gamma_gene, beta_gene, b_gene, out_gene, N);
    // cell: gc gather + LN (overwrites Y_cg/Y_gg region)
    gather_ln_k<<<gatherBlocks, 256, 0, stream>>>(recs16, beg_gc, cnt_gc, Y_gc,
                                                  nullptr, nullptr, nullptr,
                                                  gamma_cell, beta_cell, b_cell, out_cell, N);
}